// Round 14
// baseline (167.473 us; speedup 1.0000x reference)
//
#include <hip/hip_runtime.h>

#define N_PTS   524288
#define P_PTS   65536
#define B_SC    8
#define SEGS    512
#define GSEG    (B_SC*SEGS)      /* 4096 */
#define HID     256

typedef __attribute__((ext_vector_type(8))) short bf16x8;
typedef __attribute__((ext_vector_type(8))) unsigned short u16x8;
typedef __attribute__((ext_vector_type(4))) float f32x4;

__device__ __forceinline__ void bf16split(float x, unsigned short& h, unsigned short& l)
{
    const unsigned xi = __float_as_uint(x);
    const unsigned hi = (xi + 0x8000u) & 0xFFFF0000u;
    const float hf = __uint_as_float(hi);
    const float r = x - hf;
    const unsigned ri = (__float_as_uint(r) + 0x8000u) >> 16;
    h = (unsigned short)(hi >> 16);
    l = (unsigned short)(r == 0.f ? 0u : ri);
}

__device__ __forceinline__ unsigned short bf16rne(float x)
{
    const unsigned u = __float_as_uint(x);
    return (unsigned short)((u + 0x7FFFu + ((u >> 16) & 1u)) >> 16);
}

// ---------------------------------------------------------------------------
// K1 (fused): blocks 0..511 = per-block histograms of p2s;
//             blocks 512..543 = transpose W -> bf16 hi/lo.
// ---------------------------------------------------------------------------
__global__ __launch_bounds__(256) void count_convw_kernel(
    const int* __restrict__ p2s, int* __restrict__ part,
    const float* __restrict__ W0, const float* __restrict__ W1,
    const float* __restrict__ W2, const float* __restrict__ W3,
    unsigned short* __restrict__ wth0, unsigned short* __restrict__ wtl0,
    unsigned short* __restrict__ wth1, unsigned short* __restrict__ wtl1,
    unsigned short* __restrict__ wth2, unsigned short* __restrict__ wtl2,
    unsigned short* __restrict__ wth3, unsigned short* __restrict__ wtl3)
{
    __shared__ float tile[64][65];
    const int t = threadIdx.x;
    if (blockIdx.x < 512) {
        __shared__ int lc[SEGS];
        lc[t] = 0; lc[t + 256] = 0;
        __syncthreads();
        const int q0 = blockIdx.x * 1024 + t * 4;
        const int4 s4 = *reinterpret_cast<const int4*>(p2s + q0);
        atomicAdd(&lc[s4.x], 1);
        atomicAdd(&lc[s4.y], 1);
        atomicAdd(&lc[s4.z], 1);
        atomicAdd(&lc[s4.w], 1);
        __syncthreads();
        part[blockIdx.x * SEGS + t]       = lc[t];
        part[blockIdx.x * SEGS + t + 256] = lc[t + 256];
    } else {
        const int blk = blockIdx.x - 512;
        int lvl, ti;
        if (blk < 4)       { lvl = 0; ti = blk; }
        else if (blk < 8)  { lvl = 1; ti = blk - 4; }
        else if (blk < 16) { lvl = 2; ti = blk - 8; }
        else               { lvl = 3; ti = blk - 16; }
        const float* W; unsigned short *wh, *wl; int C;
        switch (lvl) {
            case 0:  W = W0; wh = wth0; wl = wtl0; C = 64;  break;
            case 1:  W = W1; wh = wth1; wl = wtl1; C = 64;  break;
            case 2:  W = W2; wh = wth2; wl = wtl2; C = 128; break;
            default: W = W3; wh = wth3; wl = wtl3; C = 256; break;
        }
        const int ktiles = C / 64;
        const int k0 = (ti % ktiles) * 64;
        const int c0 = (ti / ktiles) * 64;
        const int tw = t >> 6, tl = t & 63;
        #pragma unroll
        for (int i = 0; i < 16; ++i) {
            const int kr = tw * 16 + i;
            tile[kr][tl] = W[(size_t)(k0 + kr) * HID + c0 + tl];
        }
        __syncthreads();
        #pragma unroll
        for (int i = 0; i < 16; ++i) {
            const int cr = tw * 16 + i;
            const float x = tile[tl][cr];
            unsigned short h, l;
            bf16split(x, h, l);
            wh[(size_t)(c0 + cr) * C + k0 + tl] = h;
            wl[(size_t)(c0 + cr) * C + k0 + tl] = l;
        }
    }
}

// ---------------------------------------------------------------------------
// K2: row-sum partials (emitting per-block within-scene prefix -> bases)
//     -> exclusive scan over 4096 seg counts (single block).
// ---------------------------------------------------------------------------
__global__ __launch_bounds__(1024) void scan_kernel(
    const int* __restrict__ part, int* __restrict__ offs, int* __restrict__ bases)
{
    __shared__ int scnt[GSEG];
    __shared__ int tmp[1024];
    const int t = threadIdx.x;
    const int k = t & 511;
    const int h = t >> 9;
    #pragma unroll
    for (int j = 0; j < 4; ++j) {
        const int scene = h + j * 2;
        const int* pp = part + (scene * 64) * SEGS + k;
        int* bb = bases + (scene * 64) * SEGS + k;
        int s = 0;
        #pragma unroll 8
        for (int b = 0; b < 64; ++b) {
            bb[b * SEGS] = s;            // within-scene exclusive prefix
            s += pp[b * SEGS];
        }
        scnt[scene * SEGS + k] = s;
    }
    __syncthreads();
    int v[4]; int s = 0;
    #pragma unroll
    for (int i = 0; i < 4; ++i) { v[i] = scnt[t*4 + i]; s += v[i]; }
    tmp[t] = s;
    __syncthreads();
    for (int off = 1; off < 1024; off <<= 1) {
        int x = (t >= off) ? tmp[t - off] : 0;
        __syncthreads();
        tmp[t] += x;
        __syncthreads();
    }
    int excl = (t > 0) ? tmp[t-1] : 0;
    #pragma unroll
    for (int i = 0; i < 4; ++i) {
        offs[t*4 + i] = excl;
        excl += v[i];
    }
    if (t == 1023) offs[4096] = excl;
}

// ---------------------------------------------------------------------------
// K3 (fused): blocks 0..511 = compose+scatter (bases precomputed by scan);
// blocks 512..4095 = fp32 -> bf16 table conversion.
// ---------------------------------------------------------------------------
__global__ __launch_bounds__(256) void build_f2b_kernel(
    const int* __restrict__ inv1, const int* __restrict__ inv2,
    const int* __restrict__ inv3, const int* __restrict__ p2s,
    const int* __restrict__ bases, const int* __restrict__ offs,
    int* __restrict__ s0, int* __restrict__ s1,
    int* __restrict__ s2, int* __restrict__ s3,
    const float* __restrict__ f1, const float* __restrict__ f2,
    const float* __restrict__ f3,
    unsigned short* __restrict__ o1, unsigned short* __restrict__ o2,
    unsigned short* __restrict__ o3)
{
    const int t = threadIdx.x;
    if (blockIdx.x < 512) {
        __shared__ int lc[SEGS];
        const int blk = blockIdx.x;
        const int scene = blk >> 6;
        lc[t]       = offs[scene * SEGS + t]       + bases[blk * SEGS + t];
        lc[t + 256] = offs[scene * SEGS + t + 256] + bases[blk * SEGS + t + 256];
        __syncthreads();

        const int q0 = blk * 1024 + t * 4;
        const int4 a4 = *reinterpret_cast<const int4*>(inv1 + q0);
        const int b0 = inv2[a4.x], b1 = inv2[a4.y], b2 = inv2[a4.z], b3 = inv2[a4.w];
        const int c0i = inv3[b0],  c1i = inv3[b1],  c2i = inv3[b2],  c3i = inv3[b3];
        const int4 sg = *reinterpret_cast<const int4*>(p2s + q0);
        const int p0 = atomicAdd(&lc[sg.x], 1);
        const int p1 = atomicAdd(&lc[sg.y], 1);
        const int p2 = atomicAdd(&lc[sg.z], 1);
        const int p3 = atomicAdd(&lc[sg.w], 1);
        s0[p0] = q0;     s1[p0] = a4.x; s2[p0] = b0; s3[p0] = c0i;
        s0[p1] = q0 + 1; s1[p1] = a4.y; s2[p1] = b1; s3[p1] = c1i;
        s0[p2] = q0 + 2; s1[p2] = a4.z; s2[p2] = b2; s3[p2] = c2i;
        s0[p3] = q0 + 3; s1[p3] = a4.w; s2[p3] = b3; s3[p3] = c3i;
    } else {
        const int b1 = blockIdx.x - 512;
        const float4* in; ushort4* out; int base;
        if (b1 < 2048)      { in = (const float4*)f1; out = (ushort4*)o1; base = b1 * 1024; }
        else if (b1 < 3072) { in = (const float4*)f2; out = (ushort4*)o2; base = (b1 - 2048) * 1024; }
        else                { in = (const float4*)f3; out = (ushort4*)o3; base = (b1 - 3072) * 1024; }
        #pragma unroll
        for (int j = 0; j < 4; ++j) {
            const int i = base + j * 256 + t;
            const float4 v = in[i];
            ushort4 o;
            o.x = bf16rne(v.x); o.y = bf16rne(v.y); o.z = bf16rne(v.z); o.w = bf16rne(v.w);
            out[i] = o;
        }
    }
}

// ---------------------------------------------------------------------------
// K4: mega reduce, level-phased grid (r13 form — ties best).
// ---------------------------------------------------------------------------
__device__ __forceinline__ void reduce_body_f32(
    const float* __restrict__ fb, const int* __restrict__ sl,
    int start, int end, int g, int* s_idx, float (*s_red)[9],
    unsigned short* __restrict__ mh, unsigned short* __restrict__ ml)
{
    constexpr int CL = 16, NS = 16, C = 64;
    const int t = threadIdx.x;
    const int slot = t / CL;
    const int coff = (t % CL) * 4;
    float ax = 0.f, ay = 0.f, az = 0.f, aw = 0.f;
    for (int cs = start; cs < end; cs += 512) {
        const int n = min(512, end - cs);
        __syncthreads();
        for (int i = t; i < n; i += 256) s_idx[i] = sl[cs + i];
        __syncthreads();
        int k = slot;
        for (; k + 7*NS < n; k += 8*NS) {
            f32x4 v[8];
            #pragma unroll
            for (int u = 0; u < 8; ++u)
                v[u] = __builtin_nontemporal_load(
                    reinterpret_cast<const f32x4*>(fb + (size_t)s_idx[k + u*NS] * C + coff));
            #pragma unroll
            for (int u = 0; u < 8; ++u) {
                ax += v[u].x; ay += v[u].y; az += v[u].z; aw += v[u].w;
            }
        }
        for (; k < n; k += NS) {
            const f32x4 v0 = __builtin_nontemporal_load(
                reinterpret_cast<const f32x4*>(fb + (size_t)s_idx[k] * C + coff));
            ax += v0.x; ay += v0.y; az += v0.z; aw += v0.w;
        }
    }
    s_red[t][0] = ax; s_red[t][1] = ay; s_red[t][2] = az; s_red[t][3] = aw;
    __syncthreads();
    if (t < CL) {
        float s[4] = {s_red[t][0], s_red[t][1], s_red[t][2], s_red[t][3]};
        for (int sl2 = 1; sl2 < NS; ++sl2) {
            #pragma unroll
            for (int e = 0; e < 4; ++e) s[e] += s_red[sl2*CL + t][e];
        }
        const float inv = 1.0f / fmaxf((float)(end - start), 1.0f);
        ushort4 h4, l4;
        bf16split(s[0]*inv, h4.x, l4.x);
        bf16split(s[1]*inv, h4.y, l4.y);
        bf16split(s[2]*inv, h4.z, l4.z);
        bf16split(s[3]*inv, h4.w, l4.w);
        *reinterpret_cast<ushort4*>(mh + (size_t)g * C + t * 4) = h4;
        *reinterpret_cast<ushort4*>(ml + (size_t)g * C + t * 4) = l4;
    }
}

template<int C>
__device__ __forceinline__ void reduce_body_bf16(
    const unsigned short* __restrict__ fb, const int* __restrict__ sl,
    int start, int end, int g, int* s_idx, float (*s_red)[9],
    unsigned short* __restrict__ mh, unsigned short* __restrict__ ml)
{
    constexpr int CL = C / 8;
    constexpr int NS = 256 / CL;
    const int t = threadIdx.x;
    const int slot = t / CL;
    const int coff = (t % CL) * 8;
    float a[8];
    #pragma unroll
    for (int e = 0; e < 8; ++e) a[e] = 0.f;
    for (int cs = start; cs < end; cs += 512) {
        const int n = min(512, end - cs);
        __syncthreads();
        for (int i = t; i < n; i += 256) s_idx[i] = sl[cs + i];
        __syncthreads();
        int k = slot;
        for (; k + 7*NS < n; k += 8*NS) {
            u16x8 u[8];
            #pragma unroll
            for (int q = 0; q < 8; ++q)
                u[q] = *reinterpret_cast<const u16x8*>(fb + (size_t)s_idx[k + q*NS] * C + coff);
            #pragma unroll
            for (int q = 0; q < 8; ++q) {
                #pragma unroll
                for (int e = 0; e < 8; ++e)
                    a[e] += __uint_as_float((unsigned)u[q][e] << 16);
            }
        }
        for (; k < n; k += NS) {
            const u16x8 u0 = *reinterpret_cast<const u16x8*>(fb + (size_t)s_idx[k] * C + coff);
            #pragma unroll
            for (int e = 0; e < 8; ++e)
                a[e] += __uint_as_float((unsigned)u0[e] << 16);
        }
    }
    #pragma unroll
    for (int e = 0; e < 8; ++e) s_red[t][e] = a[e];
    __syncthreads();
    if (t < CL) {
        float s[8];
        #pragma unroll
        for (int e = 0; e < 8; ++e) s[e] = s_red[t][e];
        for (int sl2 = 1; sl2 < NS; ++sl2) {
            #pragma unroll
            for (int e = 0; e < 8; ++e) s[e] += s_red[sl2*CL + t][e];
        }
        const float inv = 1.0f / fmaxf((float)(end - start), 1.0f);
        u16x8 h8, l8;
        #pragma unroll
        for (int e = 0; e < 8; ++e) {
            unsigned short h, l;
            bf16split(s[e] * inv, h, l);
            h8[e] = h; l8[e] = l;
        }
        *reinterpret_cast<u16x8*>(mh + (size_t)g * C + coff) = h8;
        *reinterpret_cast<u16x8*>(ml + (size_t)g * C + coff) = l8;
    }
}

__global__ __launch_bounds__(256) void mega_reduce_kernel(
    const float* __restrict__ f0,
    const unsigned short* __restrict__ fb1, const unsigned short* __restrict__ fb2,
    const unsigned short* __restrict__ fb3,
    const int* __restrict__ s0, const int* __restrict__ s1,
    const int* __restrict__ s2, const int* __restrict__ s3,
    const int* __restrict__ offs,
    unsigned short* __restrict__ mh0, unsigned short* __restrict__ ml0,
    unsigned short* __restrict__ mh1, unsigned short* __restrict__ ml1,
    unsigned short* __restrict__ mh2, unsigned short* __restrict__ ml2,
    unsigned short* __restrict__ mh3, unsigned short* __restrict__ ml3)
{
    __shared__ int   s_idx[512];
    __shared__ float s_red[256][9];
    const int blk = blockIdx.x;          // grid = 16384, level-phased
    const int level = 3 - (blk >> 12);   // 3,2,1,0 phases
    const int g = blk & 4095;
    const int start = offs[g], end = offs[g+1];
    if (level == 0)      reduce_body_f32      (f0,  s0, start, end, g, s_idx, s_red, mh0, ml0);
    else if (level == 1) reduce_body_bf16<64 >(fb1, s1, start, end, g, s_idx, s_red, mh1, ml1);
    else if (level == 2) reduce_body_bf16<128>(fb2, s2, start, end, g, s_idx, s_red, mh2, ml2);
    else                 reduce_body_bf16<256>(fb3, s3, start, end, g, s_idx, s_red, mh3, ml3);
}

// ---------------------------------------------------------------------------
// K5: MFMA GEMM (bf16 hi/lo x3 passes) + bias + LayerNorm
// ---------------------------------------------------------------------------
template<int C>
__device__ __forceinline__ void gemm_ln_mfma_body(
    float* sh, int row0,
    const unsigned short* __restrict__ mh, const unsigned short* __restrict__ ml,
    const unsigned short* __restrict__ wth, const unsigned short* __restrict__ wtl,
    const float* __restrict__ bias, const float* __restrict__ gma,
    const float* __restrict__ bta, float* __restrict__ out)
{
    constexpr int KS = C / 32;
    const int t = threadIdx.x;
    const int w = t >> 6, l = t & 63;
    const int arow = row0 + w * 16 + (l & 15);
    const int kgrp = (l >> 4) * 8;

    bf16x8 Ah[KS], Al[KS];
    #pragma unroll
    for (int s = 0; s < KS; ++s) {
        Ah[s] = *reinterpret_cast<const bf16x8*>(mh + (size_t)arow * C + s * 32 + kgrp);
        Al[s] = *reinterpret_cast<const bf16x8*>(ml + (size_t)arow * C + s * 32 + kgrp);
    }

    #pragma unroll
    for (int ct = 0; ct < 16; ++ct) {
        const int bcol = ct * 16 + (l & 15);
        f32x4 acc = {0.f, 0.f, 0.f, 0.f};
        #pragma unroll
        for (int s = 0; s < KS; ++s) {
            const bf16x8 Bh = *reinterpret_cast<const bf16x8*>(wth + (size_t)bcol * C + s * 32 + kgrp);
            const bf16x8 Bl = *reinterpret_cast<const bf16x8*>(wtl + (size_t)bcol * C + s * 32 + kgrp);
            acc = __builtin_amdgcn_mfma_f32_16x16x32_bf16(Al[s], Bh, acc, 0, 0, 0);
            acc = __builtin_amdgcn_mfma_f32_16x16x32_bf16(Ah[s], Bl, acc, 0, 0, 0);
            acc = __builtin_amdgcn_mfma_f32_16x16x32_bf16(Ah[s], Bh, acc, 0, 0, 0);
        }
        const int lrow = w * 16 + (l >> 4) * 4;
        const int lcol = ct * 16 + (l & 15);
        #pragma unroll
        for (int v = 0; v < 4; ++v) sh[(lrow + v) * HID + lcol] = acc[v];
    }
    __syncthreads();

    const int lane = l;
    const float b0 = bias[lane], b1 = bias[lane + 64], b2 = bias[lane + 128], b3 = bias[lane + 192];
    const float g0 = gma[lane],  g1 = gma[lane + 64],  g2 = gma[lane + 128],  g3 = gma[lane + 192];
    const float t0 = bta[lane],  t1 = bta[lane + 64],  t2 = bta[lane + 128],  t3 = bta[lane + 192];
    for (int r = w * 16; r < w * 16 + 16; ++r) {
        const float* row = sh + r * HID;
        const float v0 = row[lane      ] + b0;
        const float v1 = row[lane + 64 ] + b1;
        const float v2 = row[lane + 128] + b2;
        const float v3 = row[lane + 192] + b3;
        float s  = v0 + v1 + v2 + v3;
        float sq = v0*v0 + v1*v1 + v2*v2 + v3*v3;
        #pragma unroll
        for (int o = 32; o > 0; o >>= 1) {
            s  += __shfl_xor(s,  o);
            sq += __shfl_xor(sq, o);
        }
        const float mean = s * (1.0f / 256.0f);
        const float var  = sq * (1.0f / 256.0f) - mean * mean;
        const float rs   = rsqrtf(var + 1e-5f);
        float* o_ = out + ((size_t)(row0 + r)) * HID;
        o_[lane      ] = (v0 - mean) * rs * g0 + t0;
        o_[lane + 64 ] = (v1 - mean) * rs * g1 + t1;
        o_[lane + 128] = (v2 - mean) * rs * g2 + t2;
        o_[lane + 192] = (v3 - mean) * rs * g3 + t3;
    }
}

__global__ __launch_bounds__(256) void gemm_ln_mfma_kernel(
    const unsigned short* __restrict__ mh0, const unsigned short* __restrict__ ml0,
    const unsigned short* __restrict__ mh1, const unsigned short* __restrict__ ml1,
    const unsigned short* __restrict__ mh2, const unsigned short* __restrict__ ml2,
    const unsigned short* __restrict__ mh3, const unsigned short* __restrict__ ml3,
    const unsigned short* __restrict__ wth0, const unsigned short* __restrict__ wtl0,
    const unsigned short* __restrict__ wth1, const unsigned short* __restrict__ wtl1,
    const unsigned short* __restrict__ wth2, const unsigned short* __restrict__ wtl2,
    const unsigned short* __restrict__ wth3, const unsigned short* __restrict__ wtl3,
    const float* __restrict__ b0, const float* __restrict__ g0, const float* __restrict__ bt0,
    const float* __restrict__ b1, const float* __restrict__ g1, const float* __restrict__ bt1,
    const float* __restrict__ b2, const float* __restrict__ g2, const float* __restrict__ bt2,
    const float* __restrict__ b3, const float* __restrict__ g3, const float* __restrict__ bt3,
    float* __restrict__ out)
{
    __shared__ float sh[64 * HID];
    const int blk = blockIdx.x;
    const int level = blk & 3;
    const int row0 = (blk >> 2) * 64;
    const size_t slab = (size_t)GSEG * HID;
    switch (level) {
        case 0: gemm_ln_mfma_body<64 >(sh, row0, mh0, ml0, wth0, wtl0, b0, g0, bt0, out + 3*slab); break;
        case 1: gemm_ln_mfma_body<64 >(sh, row0, mh1, ml1, wth1, wtl1, b1, g1, bt1, out + 2*slab); break;
        case 2: gemm_ln_mfma_body<128>(sh, row0, mh2, ml2, wth2, wtl2, b2, g2, bt2, out + 1*slab); break;
        default: gemm_ln_mfma_body<256>(sh, row0, mh3, ml3, wth3, wtl3, b3, g3, bt3, out); break;
    }
}

// ---------------------------------------------------------------------------
extern "C" void kernel_launch(void* const* d_in, const int* in_sizes, int n_in,
                              void* d_out, int out_size, void* d_ws, size_t ws_size,
                              hipStream_t stream)
{
    const float* f0  = (const float*)d_in[0];
    const float* f1  = (const float*)d_in[1];
    const float* f2  = (const float*)d_in[2];
    const float* f3  = (const float*)d_in[3];
    const int* inv1  = (const int*)d_in[4];
    const int* inv2  = (const int*)d_in[5];
    const int* inv3  = (const int*)d_in[6];
    const int* p2s   = (const int*)d_in[7];
    const float* W0  = (const float*)d_in[8];
    const float* b0  = (const float*)d_in[9];
    const float* g0  = (const float*)d_in[10];
    const float* bt0 = (const float*)d_in[11];
    const float* W1  = (const float*)d_in[12];
    const float* b1  = (const float*)d_in[13];
    const float* g1  = (const float*)d_in[14];
    const float* bt1 = (const float*)d_in[15];
    const float* W2  = (const float*)d_in[16];
    const float* b2  = (const float*)d_in[17];
    const float* g2  = (const float*)d_in[18];
    const float* bt2 = (const float*)d_in[19];
    const float* W3  = (const float*)d_in[20];
    const float* b3  = (const float*)d_in[21];
    const float* g3  = (const float*)d_in[22];
    const float* bt3 = (const float*)d_in[23];
    float* out = (float*)d_out;

    char* ws = (char*)d_ws;
    int*   s0     = (int*)(ws);                            // 2 MB
    int*   s1     = (int*)(ws + (2u<<20));                 // 2 MB
    int*   s2     = (int*)(ws + (4u<<20));                 // 2 MB
    int*   s3     = (int*)(ws + (6u<<20));                 // 2 MB
    int*   part   = (int*)(ws + (8u<<20));                 // 1 MB
    int*   offs   = (int*)(ws + (9u<<20));                 // 16.4 KB
    unsigned short* mh0 = (unsigned short*)(ws + (10u<<20));
    unsigned short* mh1 = mh0 + (size_t)GSEG * 64;
    unsigned short* mh2 = mh1 + (size_t)GSEG * 64;
    unsigned short* mh3 = mh2 + (size_t)GSEG * 128;
    unsigned short* ml0 = (unsigned short*)(ws + (14u<<20));
    unsigned short* ml1 = ml0 + (size_t)GSEG * 64;
    unsigned short* ml2 = ml1 + (size_t)GSEG * 64;
    unsigned short* ml3 = ml2 + (size_t)GSEG * 128;
    unsigned short* wth0 = (unsigned short*)(ws + (18u<<20));
    unsigned short* wth1 = wth0 + 64  * HID;
    unsigned short* wth2 = wth1 + 64  * HID;
    unsigned short* wth3 = wth2 + 128 * HID;
    unsigned short* wtl0 = (unsigned short*)(ws + (18u<<20) + (512u<<10));
    unsigned short* wtl1 = wtl0 + 64  * HID;
    unsigned short* wtl2 = wtl1 + 64  * HID;
    unsigned short* wtl3 = wtl2 + 128 * HID;
    unsigned short* fb1  = (unsigned short*)(ws + (20u<<20));   // 16 MB
    unsigned short* fb2  = (unsigned short*)(ws + (36u<<20));   // 8 MB
    unsigned short* fb3  = (unsigned short*)(ws + (44u<<20));   // 4 MB
    int*   bases  = (int*)(ws + (48u<<20));                     // 1 MB

    count_convw_kernel<<<544, 256, 0, stream>>>(p2s, part,
        W0, W1, W2, W3,
        wth0, wtl0, wth1, wtl1, wth2, wtl2, wth3, wtl3);
    scan_kernel<<<1, 1024, 0, stream>>>(part, offs, bases);
    build_f2b_kernel<<<4096, 256, 0, stream>>>(inv1, inv2, inv3, p2s,
        bases, offs, s0, s1, s2, s3,
        f1, f2, f3, fb1, fb2, fb3);
    mega_reduce_kernel<<<16384, 256, 0, stream>>>(
        f0, fb1, fb2, fb3, s0, s1, s2, s3, offs,
        mh0, ml0, mh1, ml1, mh2, ml2, mh3, ml3);
    gemm_ln_mfma_kernel<<<4*GSEG/64, 256, 0, stream>>>(
        mh0, ml0, mh1, ml1, mh2, ml2, mh3, ml3,
        wth0, wtl0, wth1, wtl1, wth2, wtl2, wth3, wtl3,
        b0, g0, bt0, b1, g1, bt1, b2, g2, bt2, b3, g3, bt3, out);
}

// Round 15
// 155.893 us; speedup vs baseline: 1.0743x; 1.0743x over previous
//
#include <hip/hip_runtime.h>

#define N_PTS   524288
#define P_PTS   65536
#define B_SC    8
#define SEGS    512
#define GSEG    (B_SC*SEGS)      /* 4096 */
#define HID     256

typedef __attribute__((ext_vector_type(8))) short bf16x8;
typedef __attribute__((ext_vector_type(8))) unsigned short u16x8;
typedef __attribute__((ext_vector_type(4))) float f32x4;

__device__ __forceinline__ void bf16split(float x, unsigned short& h, unsigned short& l)
{
    const unsigned xi = __float_as_uint(x);
    const unsigned hi = (xi + 0x8000u) & 0xFFFF0000u;
    const float hf = __uint_as_float(hi);
    const float r = x - hf;
    const unsigned ri = (__float_as_uint(r) + 0x8000u) >> 16;
    h = (unsigned short)(hi >> 16);
    l = (unsigned short)(r == 0.f ? 0u : ri);
}

__device__ __forceinline__ unsigned short bf16rne(float x)
{
    const unsigned u = __float_as_uint(x);
    return (unsigned short)((u + 0x7FFFu + ((u >> 16) & 1u)) >> 16);
}

// ---------------------------------------------------------------------------
// K1 (fused): blocks 0..511 = per-block histograms of p2s;
//             blocks 512..543 = transpose W -> bf16 hi/lo.
// ---------------------------------------------------------------------------
__global__ __launch_bounds__(256) void count_convw_kernel(
    const int* __restrict__ p2s, int* __restrict__ part,
    const float* __restrict__ W0, const float* __restrict__ W1,
    const float* __restrict__ W2, const float* __restrict__ W3,
    unsigned short* __restrict__ wth0, unsigned short* __restrict__ wtl0,
    unsigned short* __restrict__ wth1, unsigned short* __restrict__ wtl1,
    unsigned short* __restrict__ wth2, unsigned short* __restrict__ wtl2,
    unsigned short* __restrict__ wth3, unsigned short* __restrict__ wtl3)
{
    __shared__ float tile[64][65];
    const int t = threadIdx.x;
    if (blockIdx.x < 512) {
        __shared__ int lc[SEGS];
        lc[t] = 0; lc[t + 256] = 0;
        __syncthreads();
        const int q0 = blockIdx.x * 1024 + t * 4;
        const int4 s4 = *reinterpret_cast<const int4*>(p2s + q0);
        atomicAdd(&lc[s4.x], 1);
        atomicAdd(&lc[s4.y], 1);
        atomicAdd(&lc[s4.z], 1);
        atomicAdd(&lc[s4.w], 1);
        __syncthreads();
        part[blockIdx.x * SEGS + t]       = lc[t];
        part[blockIdx.x * SEGS + t + 256] = lc[t + 256];
    } else {
        const int blk = blockIdx.x - 512;
        int lvl, ti;
        if (blk < 4)       { lvl = 0; ti = blk; }
        else if (blk < 8)  { lvl = 1; ti = blk - 4; }
        else if (blk < 16) { lvl = 2; ti = blk - 8; }
        else               { lvl = 3; ti = blk - 16; }
        const float* W; unsigned short *wh, *wl; int C;
        switch (lvl) {
            case 0:  W = W0; wh = wth0; wl = wtl0; C = 64;  break;
            case 1:  W = W1; wh = wth1; wl = wtl1; C = 64;  break;
            case 2:  W = W2; wh = wth2; wl = wtl2; C = 128; break;
            default: W = W3; wh = wth3; wl = wtl3; C = 256; break;
        }
        const int ktiles = C / 64;
        const int k0 = (ti % ktiles) * 64;
        const int c0 = (ti / ktiles) * 64;
        const int tw = t >> 6, tl = t & 63;
        #pragma unroll
        for (int i = 0; i < 16; ++i) {
            const int kr = tw * 16 + i;
            tile[kr][tl] = W[(size_t)(k0 + kr) * HID + c0 + tl];
        }
        __syncthreads();
        #pragma unroll
        for (int i = 0; i < 16; ++i) {
            const int cr = tw * 16 + i;
            const float x = tile[tl][cr];
            unsigned short h, l;
            bf16split(x, h, l);
            wh[(size_t)(c0 + cr) * C + k0 + tl] = h;
            wl[(size_t)(c0 + cr) * C + k0 + tl] = l;
        }
    }
}

// ---------------------------------------------------------------------------
// K2: block 0 = row sums + exclusive scan -> offs;
//     blocks 1..8 = scene s-1: within-scene per-block prefix -> bases.
// ---------------------------------------------------------------------------
__global__ __launch_bounds__(1024) void scan_kernel(
    const int* __restrict__ part, int* __restrict__ offs, int* __restrict__ bases)
{
    const int t = threadIdx.x;
    if (blockIdx.x > 0) {
        const int scene = blockIdx.x - 1;
        if (t < 512) {
            const int* pp = part + (scene * 64) * SEGS + t;
            int* bb = bases + (scene * 64) * SEGS + t;
            int s = 0;
            #pragma unroll 8
            for (int b = 0; b < 64; ++b) {
                bb[b * SEGS] = s;
                s += pp[b * SEGS];
            }
        }
        return;
    }
    __shared__ int scnt[GSEG];
    __shared__ int tmp[1024];
    const int k = t & 511;
    const int h = t >> 9;
    #pragma unroll
    for (int j = 0; j < 4; ++j) {
        const int scene = h + j * 2;
        const int* pp = part + (scene * 64) * SEGS + k;
        int s = 0;
        #pragma unroll 8
        for (int b = 0; b < 64; ++b) s += pp[b * SEGS];
        scnt[scene * SEGS + k] = s;
    }
    __syncthreads();
    int v[4]; int s = 0;
    #pragma unroll
    for (int i = 0; i < 4; ++i) { v[i] = scnt[t*4 + i]; s += v[i]; }
    tmp[t] = s;
    __syncthreads();
    for (int off = 1; off < 1024; off <<= 1) {
        int x = (t >= off) ? tmp[t - off] : 0;
        __syncthreads();
        tmp[t] += x;
        __syncthreads();
    }
    int excl = (t > 0) ? tmp[t-1] : 0;
    #pragma unroll
    for (int i = 0; i < 4; ++i) {
        offs[t*4 + i] = excl;
        excl += v[i];
    }
    if (t == 1023) offs[4096] = excl;
}

// ---------------------------------------------------------------------------
// K3 (fused): blocks 0..511 = compose+scatter (bases precomputed by scan);
// blocks 512..4095 = fp32 -> bf16 table conversion.
// ---------------------------------------------------------------------------
__global__ __launch_bounds__(256) void build_f2b_kernel(
    const int* __restrict__ inv1, const int* __restrict__ inv2,
    const int* __restrict__ inv3, const int* __restrict__ p2s,
    const int* __restrict__ bases, const int* __restrict__ offs,
    int* __restrict__ s0, int* __restrict__ s1,
    int* __restrict__ s2, int* __restrict__ s3,
    const float* __restrict__ f1, const float* __restrict__ f2,
    const float* __restrict__ f3,
    unsigned short* __restrict__ o1, unsigned short* __restrict__ o2,
    unsigned short* __restrict__ o3)
{
    const int t = threadIdx.x;
    if (blockIdx.x < 512) {
        __shared__ int lc[SEGS];
        const int blk = blockIdx.x;
        const int scene = blk >> 6;
        lc[t]       = offs[scene * SEGS + t]       + bases[blk * SEGS + t];
        lc[t + 256] = offs[scene * SEGS + t + 256] + bases[blk * SEGS + t + 256];
        __syncthreads();

        const int q0 = blk * 1024 + t * 4;
        const int4 a4 = *reinterpret_cast<const int4*>(inv1 + q0);
        const int b0 = inv2[a4.x], b1 = inv2[a4.y], b2 = inv2[a4.z], b3 = inv2[a4.w];
        const int c0i = inv3[b0],  c1i = inv3[b1],  c2i = inv3[b2],  c3i = inv3[b3];
        const int4 sg = *reinterpret_cast<const int4*>(p2s + q0);
        const int p0 = atomicAdd(&lc[sg.x], 1);
        const int p1 = atomicAdd(&lc[sg.y], 1);
        const int p2 = atomicAdd(&lc[sg.z], 1);
        const int p3 = atomicAdd(&lc[sg.w], 1);
        s0[p0] = q0;     s1[p0] = a4.x; s2[p0] = b0; s3[p0] = c0i;
        s0[p1] = q0 + 1; s1[p1] = a4.y; s2[p1] = b1; s3[p1] = c1i;
        s0[p2] = q0 + 2; s1[p2] = a4.z; s2[p2] = b2; s3[p2] = c2i;
        s0[p3] = q0 + 3; s1[p3] = a4.w; s2[p3] = b3; s3[p3] = c3i;
    } else {
        const int b1 = blockIdx.x - 512;
        const float4* in; ushort4* out; int base;
        if (b1 < 2048)      { in = (const float4*)f1; out = (ushort4*)o1; base = b1 * 1024; }
        else if (b1 < 3072) { in = (const float4*)f2; out = (ushort4*)o2; base = (b1 - 2048) * 1024; }
        else                { in = (const float4*)f3; out = (ushort4*)o3; base = (b1 - 3072) * 1024; }
        #pragma unroll
        for (int j = 0; j < 4; ++j) {
            const int i = base + j * 256 + t;
            const float4 v = in[i];
            ushort4 o;
            o.x = bf16rne(v.x); o.y = bf16rne(v.y); o.z = bf16rne(v.z); o.w = bf16rne(v.w);
            out[i] = o;
        }
    }
}

// ---------------------------------------------------------------------------
// K4: mega reduce, level-phased grid (r13 form — best measured).
// ---------------------------------------------------------------------------
__device__ __forceinline__ void reduce_body_f32(
    const float* __restrict__ fb, const int* __restrict__ sl,
    int start, int end, int g, int* s_idx, float (*s_red)[9],
    unsigned short* __restrict__ mh, unsigned short* __restrict__ ml)
{
    constexpr int CL = 16, NS = 16, C = 64;
    const int t = threadIdx.x;
    const int slot = t / CL;
    const int coff = (t % CL) * 4;
    float ax = 0.f, ay = 0.f, az = 0.f, aw = 0.f;
    for (int cs = start; cs < end; cs += 512) {
        const int n = min(512, end - cs);
        __syncthreads();
        for (int i = t; i < n; i += 256) s_idx[i] = sl[cs + i];
        __syncthreads();
        int k = slot;
        for (; k + 7*NS < n; k += 8*NS) {
            f32x4 v[8];
            #pragma unroll
            for (int u = 0; u < 8; ++u)
                v[u] = __builtin_nontemporal_load(
                    reinterpret_cast<const f32x4*>(fb + (size_t)s_idx[k + u*NS] * C + coff));
            #pragma unroll
            for (int u = 0; u < 8; ++u) {
                ax += v[u].x; ay += v[u].y; az += v[u].z; aw += v[u].w;
            }
        }
        for (; k < n; k += NS) {
            const f32x4 v0 = __builtin_nontemporal_load(
                reinterpret_cast<const f32x4*>(fb + (size_t)s_idx[k] * C + coff));
            ax += v0.x; ay += v0.y; az += v0.z; aw += v0.w;
        }
    }
    s_red[t][0] = ax; s_red[t][1] = ay; s_red[t][2] = az; s_red[t][3] = aw;
    __syncthreads();
    if (t < CL) {
        float s[4] = {s_red[t][0], s_red[t][1], s_red[t][2], s_red[t][3]};
        for (int sl2 = 1; sl2 < NS; ++sl2) {
            #pragma unroll
            for (int e = 0; e < 4; ++e) s[e] += s_red[sl2*CL + t][e];
        }
        const float inv = 1.0f / fmaxf((float)(end - start), 1.0f);
        ushort4 h4, l4;
        bf16split(s[0]*inv, h4.x, l4.x);
        bf16split(s[1]*inv, h4.y, l4.y);
        bf16split(s[2]*inv, h4.z, l4.z);
        bf16split(s[3]*inv, h4.w, l4.w);
        *reinterpret_cast<ushort4*>(mh + (size_t)g * C + t * 4) = h4;
        *reinterpret_cast<ushort4*>(ml + (size_t)g * C + t * 4) = l4;
    }
}

template<int C>
__device__ __forceinline__ void reduce_body_bf16(
    const unsigned short* __restrict__ fb, const int* __restrict__ sl,
    int start, int end, int g, int* s_idx, float (*s_red)[9],
    unsigned short* __restrict__ mh, unsigned short* __restrict__ ml)
{
    constexpr int CL = C / 8;
    constexpr int NS = 256 / CL;
    const int t = threadIdx.x;
    const int slot = t / CL;
    const int coff = (t % CL) * 8;
    float a[8];
    #pragma unroll
    for (int e = 0; e < 8; ++e) a[e] = 0.f;
    for (int cs = start; cs < end; cs += 512) {
        const int n = min(512, end - cs);
        __syncthreads();
        for (int i = t; i < n; i += 256) s_idx[i] = sl[cs + i];
        __syncthreads();
        int k = slot;
        for (; k + 7*NS < n; k += 8*NS) {
            u16x8 u[8];
            #pragma unroll
            for (int q = 0; q < 8; ++q)
                u[q] = *reinterpret_cast<const u16x8*>(fb + (size_t)s_idx[k + q*NS] * C + coff);
            #pragma unroll
            for (int q = 0; q < 8; ++q) {
                #pragma unroll
                for (int e = 0; e < 8; ++e)
                    a[e] += __uint_as_float((unsigned)u[q][e] << 16);
            }
        }
        for (; k < n; k += NS) {
            const u16x8 u0 = *reinterpret_cast<const u16x8*>(fb + (size_t)s_idx[k] * C + coff);
            #pragma unroll
            for (int e = 0; e < 8; ++e)
                a[e] += __uint_as_float((unsigned)u0[e] << 16);
        }
    }
    #pragma unroll
    for (int e = 0; e < 8; ++e) s_red[t][e] = a[e];
    __syncthreads();
    if (t < CL) {
        float s[8];
        #pragma unroll
        for (int e = 0; e < 8; ++e) s[e] = s_red[t][e];
        for (int sl2 = 1; sl2 < NS; ++sl2) {
            #pragma unroll
            for (int e = 0; e < 8; ++e) s[e] += s_red[sl2*CL + t][e];
        }
        const float inv = 1.0f / fmaxf((float)(end - start), 1.0f);
        u16x8 h8, l8;
        #pragma unroll
        for (int e = 0; e < 8; ++e) {
            unsigned short h, l;
            bf16split(s[e] * inv, h, l);
            h8[e] = h; l8[e] = l;
        }
        *reinterpret_cast<u16x8*>(mh + (size_t)g * C + coff) = h8;
        *reinterpret_cast<u16x8*>(ml + (size_t)g * C + coff) = l8;
    }
}

__global__ __launch_bounds__(256) void mega_reduce_kernel(
    const float* __restrict__ f0,
    const unsigned short* __restrict__ fb1, const unsigned short* __restrict__ fb2,
    const unsigned short* __restrict__ fb3,
    const int* __restrict__ s0, const int* __restrict__ s1,
    const int* __restrict__ s2, const int* __restrict__ s3,
    const int* __restrict__ offs,
    unsigned short* __restrict__ mh0, unsigned short* __restrict__ ml0,
    unsigned short* __restrict__ mh1, unsigned short* __restrict__ ml1,
    unsigned short* __restrict__ mh2, unsigned short* __restrict__ ml2,
    unsigned short* __restrict__ mh3, unsigned short* __restrict__ ml3)
{
    __shared__ int   s_idx[512];
    __shared__ float s_red[256][9];
    const int blk = blockIdx.x;          // grid = 16384, level-phased
    const int level = 3 - (blk >> 12);   // 3,2,1,0 phases
    const int g = blk & 4095;
    const int start = offs[g], end = offs[g+1];
    if (level == 0)      reduce_body_f32      (f0,  s0, start, end, g, s_idx, s_red, mh0, ml0);
    else if (level == 1) reduce_body_bf16<64 >(fb1, s1, start, end, g, s_idx, s_red, mh1, ml1);
    else if (level == 2) reduce_body_bf16<128>(fb2, s2, start, end, g, s_idx, s_red, mh2, ml2);
    else                 reduce_body_bf16<256>(fb3, s3, start, end, g, s_idx, s_red, mh3, ml3);
}

// ---------------------------------------------------------------------------
// K5: MFMA GEMM (bf16 hi/lo x3 passes) + bias + LayerNorm
// ---------------------------------------------------------------------------
template<int C>
__device__ __forceinline__ void gemm_ln_mfma_body(
    float* sh, int row0,
    const unsigned short* __restrict__ mh, const unsigned short* __restrict__ ml,
    const unsigned short* __restrict__ wth, const unsigned short* __restrict__ wtl,
    const float* __restrict__ bias, const float* __restrict__ gma,
    const float* __restrict__ bta, float* __restrict__ out)
{
    constexpr int KS = C / 32;
    const int t = threadIdx.x;
    const int w = t >> 6, l = t & 63;
    const int arow = row0 + w * 16 + (l & 15);
    const int kgrp = (l >> 4) * 8;

    bf16x8 Ah[KS], Al[KS];
    #pragma unroll
    for (int s = 0; s < KS; ++s) {
        Ah[s] = *reinterpret_cast<const bf16x8*>(mh + (size_t)arow * C + s * 32 + kgrp);
        Al[s] = *reinterpret_cast<const bf16x8*>(ml + (size_t)arow * C + s * 32 + kgrp);
    }

    #pragma unroll
    for (int ct = 0; ct < 16; ++ct) {
        const int bcol = ct * 16 + (l & 15);
        f32x4 acc = {0.f, 0.f, 0.f, 0.f};
        #pragma unroll
        for (int s = 0; s < KS; ++s) {
            const bf16x8 Bh = *reinterpret_cast<const bf16x8*>(wth + (size_t)bcol * C + s * 32 + kgrp);
            const bf16x8 Bl = *reinterpret_cast<const bf16x8*>(wtl + (size_t)bcol * C + s * 32 + kgrp);
            acc = __builtin_amdgcn_mfma_f32_16x16x32_bf16(Al[s], Bh, acc, 0, 0, 0);
            acc = __builtin_amdgcn_mfma_f32_16x16x32_bf16(Ah[s], Bl, acc, 0, 0, 0);
            acc = __builtin_amdgcn_mfma_f32_16x16x32_bf16(Ah[s], Bh, acc, 0, 0, 0);
        }
        const int lrow = w * 16 + (l >> 4) * 4;
        const int lcol = ct * 16 + (l & 15);
        #pragma unroll
        for (int v = 0; v < 4; ++v) sh[(lrow + v) * HID + lcol] = acc[v];
    }
    __syncthreads();

    const int lane = l;
    const float b0 = bias[lane], b1 = bias[lane + 64], b2 = bias[lane + 128], b3 = bias[lane + 192];
    const float g0 = gma[lane],  g1 = gma[lane + 64],  g2 = gma[lane + 128],  g3 = gma[lane + 192];
    const float t0 = bta[lane],  t1 = bta[lane + 64],  t2 = bta[lane + 128],  t3 = bta[lane + 192];
    for (int r = w * 16; r < w * 16 + 16; ++r) {
        const float* row = sh + r * HID;
        const float v0 = row[lane      ] + b0;
        const float v1 = row[lane + 64 ] + b1;
        const float v2 = row[lane + 128] + b2;
        const float v3 = row[lane + 192] + b3;
        float s  = v0 + v1 + v2 + v3;
        float sq = v0*v0 + v1*v1 + v2*v2 + v3*v3;
        #pragma unroll
        for (int o = 32; o > 0; o >>= 1) {
            s  += __shfl_xor(s,  o);
            sq += __shfl_xor(sq, o);
        }
        const float mean = s * (1.0f / 256.0f);
        const float var  = sq * (1.0f / 256.0f) - mean * mean;
        const float rs   = rsqrtf(var + 1e-5f);
        float* o_ = out + ((size_t)(row0 + r)) * HID;
        o_[lane      ] = (v0 - mean) * rs * g0 + t0;
        o_[lane + 64 ] = (v1 - mean) * rs * g1 + t1;
        o_[lane + 128] = (v2 - mean) * rs * g2 + t2;
        o_[lane + 192] = (v3 - mean) * rs * g3 + t3;
    }
}

__global__ __launch_bounds__(256) void gemm_ln_mfma_kernel(
    const unsigned short* __restrict__ mh0, const unsigned short* __restrict__ ml0,
    const unsigned short* __restrict__ mh1, const unsigned short* __restrict__ ml1,
    const unsigned short* __restrict__ mh2, const unsigned short* __restrict__ ml2,
    const unsigned short* __restrict__ mh3, const unsigned short* __restrict__ ml3,
    const unsigned short* __restrict__ wth0, const unsigned short* __restrict__ wtl0,
    const unsigned short* __restrict__ wth1, const unsigned short* __restrict__ wtl1,
    const unsigned short* __restrict__ wth2, const unsigned short* __restrict__ wtl2,
    const unsigned short* __restrict__ wth3, const unsigned short* __restrict__ wtl3,
    const float* __restrict__ b0, const float* __restrict__ g0, const float* __restrict__ bt0,
    const float* __restrict__ b1, const float* __restrict__ g1, const float* __restrict__ bt1,
    const float* __restrict__ b2, const float* __restrict__ g2, const float* __restrict__ bt2,
    const float* __restrict__ b3, const float* __restrict__ g3, const float* __restrict__ bt3,
    float* __restrict__ out)
{
    __shared__ float sh[64 * HID];
    const int blk = blockIdx.x;
    const int level = blk & 3;
    const int row0 = (blk >> 2) * 64;
    const size_t slab = (size_t)GSEG * HID;
    switch (level) {
        case 0: gemm_ln_mfma_body<64 >(sh, row0, mh0, ml0, wth0, wtl0, b0, g0, bt0, out + 3*slab); break;
        case 1: gemm_ln_mfma_body<64 >(sh, row0, mh1, ml1, wth1, wtl1, b1, g1, bt1, out + 2*slab); break;
        case 2: gemm_ln_mfma_body<128>(sh, row0, mh2, ml2, wth2, wtl2, b2, g2, bt2, out + 1*slab); break;
        default: gemm_ln_mfma_body<256>(sh, row0, mh3, ml3, wth3, wtl3, b3, g3, bt3, out); break;
    }
}

// ---------------------------------------------------------------------------
extern "C" void kernel_launch(void* const* d_in, const int* in_sizes, int n_in,
                              void* d_out, int out_size, void* d_ws, size_t ws_size,
                              hipStream_t stream)
{
    const float* f0  = (const float*)d_in[0];
    const float* f1  = (const float*)d_in[1];
    const float* f2  = (const float*)d_in[2];
    const float* f3  = (const float*)d_in[3];
    const int* inv1  = (const int*)d_in[4];
    const int* inv2  = (const int*)d_in[5];
    const int* inv3  = (const int*)d_in[6];
    const int* p2s   = (const int*)d_in[7];
    const float* W0  = (const float*)d_in[8];
    const float* b0  = (const float*)d_in[9];
    const float* g0  = (const float*)d_in[10];
    const float* bt0 = (const float*)d_in[11];
    const float* W1  = (const float*)d_in[12];
    const float* b1  = (const float*)d_in[13];
    const float* g1  = (const float*)d_in[14];
    const float* bt1 = (const float*)d_in[15];
    const float* W2  = (const float*)d_in[16];
    const float* b2  = (const float*)d_in[17];
    const float* g2  = (const float*)d_in[18];
    const float* bt2 = (const float*)d_in[19];
    const float* W3  = (const float*)d_in[20];
    const float* b3  = (const float*)d_in[21];
    const float* g3  = (const float*)d_in[22];
    const float* bt3 = (const float*)d_in[23];
    float* out = (float*)d_out;

    char* ws = (char*)d_ws;
    int*   s0     = (int*)(ws);                            // 2 MB
    int*   s1     = (int*)(ws + (2u<<20));                 // 2 MB
    int*   s2     = (int*)(ws + (4u<<20));                 // 2 MB
    int*   s3     = (int*)(ws + (6u<<20));                 // 2 MB
    int*   part   = (int*)(ws + (8u<<20));                 // 1 MB
    int*   offs   = (int*)(ws + (9u<<20));                 // 16.4 KB
    unsigned short* mh0 = (unsigned short*)(ws + (10u<<20));
    unsigned short* mh1 = mh0 + (size_t)GSEG * 64;
    unsigned short* mh2 = mh1 + (size_t)GSEG * 64;
    unsigned short* mh3 = mh2 + (size_t)GSEG * 128;
    unsigned short* ml0 = (unsigned short*)(ws + (14u<<20));
    unsigned short* ml1 = ml0 + (size_t)GSEG * 64;
    unsigned short* ml2 = ml1 + (size_t)GSEG * 64;
    unsigned short* ml3 = ml2 + (size_t)GSEG * 128;
    unsigned short* wth0 = (unsigned short*)(ws + (18u<<20));
    unsigned short* wth1 = wth0 + 64  * HID;
    unsigned short* wth2 = wth1 + 64  * HID;
    unsigned short* wth3 = wth2 + 128 * HID;
    unsigned short* wtl0 = (unsigned short*)(ws + (18u<<20) + (512u<<10));
    unsigned short* wtl1 = wtl0 + 64  * HID;
    unsigned short* wtl2 = wtl1 + 64  * HID;
    unsigned short* wtl3 = wtl2 + 128 * HID;
    unsigned short* fb1  = (unsigned short*)(ws + (20u<<20));   // 16 MB
    unsigned short* fb2  = (unsigned short*)(ws + (36u<<20));   // 8 MB
    unsigned short* fb3  = (unsigned short*)(ws + (44u<<20));   // 4 MB
    int*   bases  = (int*)(ws + (48u<<20));                     // 1 MB

    count_convw_kernel<<<544, 256, 0, stream>>>(p2s, part,
        W0, W1, W2, W3,
        wth0, wtl0, wth1, wtl1, wth2, wtl2, wth3, wtl3);
    scan_kernel<<<9, 1024, 0, stream>>>(part, offs, bases);
    build_f2b_kernel<<<4096, 256, 0, stream>>>(inv1, inv2, inv3, p2s,
        bases, offs, s0, s1, s2, s3,
        f1, f2, f3, fb1, fb2, fb3);
    mega_reduce_kernel<<<16384, 256, 0, stream>>>(
        f0, fb1, fb2, fb3, s0, s1, s2, s3, offs,
        mh0, ml0, mh1, ml1, mh2, ml2, mh3, ml3);
    gemm_ln_mfma_kernel<<<4*GSEG/64, 256, 0, stream>>>(
        mh0, ml0, mh1, ml1, mh2, ml2, mh3, ml3,
        wth0, wtl0, wth1, wtl1, wth2, wtl2, wth3, wtl3,
        b0, g0, bt0, b1, g1, bt1, b2, g2, bt2, b3, g3, bt3, out);
}